// Round 3
// baseline (107.288 us; speedup 1.0000x reference)
//
#include <hip/hip_runtime.h>
#include <hip/hip_bf16.h>

// VDEmbedding: out[t, :] = mask[x[t]] * weight[x[t], :], zero at x==PAD_IDX(0).
// Memory-bound random gather. 4 tokens per thread so each wave keeps 4
// independent 512B row-gathers in flight (MLP), plus nontemporal stores so
// the 32 MiB output stream doesn't evict weight rows from L2.
// R2->R3: use native ext_vector_type float4 for __builtin_nontemporal_store
// (HIP_vector_type<float,4> is rejected by the builtin).

#define TOKENS (16 * 4096)
#define EMBED_DIM 128
#define ROW_F4 32                   // EMBED_DIM / 4 floats per float4
#define PAD_IDX 0
#define TOK_PER_GROUP 4             // tokens handled per 32-lane group

typedef float v4f __attribute__((ext_vector_type(4)));
typedef int   v4i __attribute__((ext_vector_type(4)));

__global__ __launch_bounds__(256) void vdemb_gather4_kernel(
    const v4i* __restrict__ x4,       // [TOKENS/4] indices as int4
    const v4f* __restrict__ w4,       // [VOCAB * 32] weight as float4
    const float* __restrict__ mask,   // [VOCAB]
    v4f* __restrict__ out4)           // [TOKENS * 32]
{
    const int tid   = blockIdx.x * blockDim.x + threadIdx.x;
    const int group = tid >> 5;       // 32 lanes per group, 4 tokens per group
    const int lane  = tid & 31;

    // One 16B load fetches all 4 indices (broadcast across the 32-lane group).
    const v4i iv = x4[group];
    int idx[TOK_PER_GROUP] = {iv.x, iv.y, iv.z, iv.w};

    // 4 independent mask loads (random addrs, broadcast within group).
    float scale[TOK_PER_GROUP];
#pragma unroll
    for (int k = 0; k < TOK_PER_GROUP; ++k)
        scale[k] = (idx[k] == PAD_IDX) ? 0.0f : mask[idx[k]];

    // 4 independent 16B row-fragment gathers -> 4 x 512B in flight per wave.
    v4f w[TOK_PER_GROUP];
#pragma unroll
    for (int k = 0; k < TOK_PER_GROUP; ++k)
        w[k] = w4[(size_t)idx[k] * ROW_F4 + lane];

    const size_t base = (size_t)group * TOK_PER_GROUP * ROW_F4 + lane;
#pragma unroll
    for (int k = 0; k < TOK_PER_GROUP; ++k) {
        v4f o = w[k] * scale[k];
        // Output is write-once, never re-read: nontemporal keeps L2 for weights.
        __builtin_nontemporal_store(o, &out4[base + (size_t)k * ROW_F4]);
    }
}

extern "C" void kernel_launch(void* const* d_in, const int* in_sizes, int n_in,
                              void* d_out, int out_size, void* d_ws, size_t ws_size,
                              hipStream_t stream) {
    const v4i*   x4   = (const v4i*)d_in[0];    // [16*4096] int32 as int4
    const v4f*   w4   = (const v4f*)d_in[1];    // [128000, 128] fp32 as float4
    const float* mask = (const float*)d_in[2];  // [128000]
    v4f*         out4 = (v4f*)d_out;            // [16*4096*128] fp32 as float4

    const int groups        = TOKENS / TOK_PER_GROUP;       // 16384
    const int total_threads = groups * 32;                  // 524288
    const int block = 256;
    const int grid  = total_threads / block;                // 2048
    vdemb_gather4_kernel<<<grid, block, 0, stream>>>(x4, w4, mask, out4);
}